// Round 14
// baseline (375.571 us; speedup 1.0000x reference)
//
#include <hip/hip_runtime.h>
#include <hip/hip_bf16.h>

// ---------------------------------------------------------------------------
// E8 RHT Linear:  y = SU * FHT( FHT(SV * x) @ Wr^T * Wscale )
// Identity used:  y = (SV*x) @ W5^T,  W5 = diag(SU*Wscale) * (H Wr H)/4096
// GEMM: r5/r9-exact K-loop (frozen) + LDS-transpose epilogue with float4
// C stores (full-line writes). r14: fix LDS transpose stride 68 -> 260.
// ---------------------------------------------------------------------------

using short8   = __attribute__((ext_vector_type(8))) short;
using f32x4    = __attribute__((ext_vector_type(4))) float;
using ushort4v = __attribute__((ext_vector_type(4))) unsigned short;

#define AS1 __attribute__((address_space(1)))
#define AS3 __attribute__((address_space(3)))

__device__ __forceinline__ unsigned short f2bf(float f) {
  unsigned int u = __float_as_uint(f);
  unsigned int r = (u + 0x7fffu + ((u >> 16) & 1u)) >> 16;
  return (unsigned short)r;
}

__device__ __forceinline__ float bf2f(unsigned short u) {
  return __uint_as_float((unsigned int)u << 16);
}

__device__ __forceinline__ void gload16(const void* g, void* l) {
  __builtin_amdgcn_global_load_lds((const AS1 void*)g, (AS3 void*)l, 16, 0, 0);
}

#define WAIT_VM4 asm volatile("s_waitcnt vmcnt(4)" ::: "memory")
#define WAIT_VM0 asm volatile("s_waitcnt vmcnt(0)" ::: "memory")
#define LGKM0    asm volatile("s_waitcnt lgkmcnt(0)" ::: "memory")
#define SB       __builtin_amdgcn_sched_barrier(0)
#define BAR      __builtin_amdgcn_s_barrier()
#define PRIO1    __builtin_amdgcn_s_setprio(1)
#define PRIO0    __builtin_amdgcn_s_setprio(0)

// H16 butterflies over register index j (elem distance 1,2,4,8)
#define H16_REGS(v)                                                       \
  _Pragma("unroll")                                                       \
  for (int d = 1; d < 16; d <<= 1) {                                      \
    _Pragma("unroll")                                                     \
    for (int j = 0; j < 16; ++j) {                                        \
      if ((j & d) == 0) {                                                 \
        float a_ = v[j], b_ = v[j | d];                                   \
        v[j] = a_ + b_;                                                   \
        v[j | d] = a_ - b_;                                               \
      }                                                                   \
    }                                                                     \
  }

// ---------------------------------------------------------------------------
// Kernel 1: z = bf16(SV * x), pure elementwise. 16 elems/thread.
// ---------------------------------------------------------------------------
__global__ __launch_bounds__(256) void zconv_kernel(const float* __restrict__ X,
                                                    const float* __restrict__ SV,
                                                    unsigned short* __restrict__ Z) {
  const size_t idx = ((size_t)blockIdx.x * 256 + threadIdx.x) * 16;
  const int c0 = (int)(idx & 4095);
  const float4* X4 = (const float4*)(X + idx);
  const float4* SV4 = (const float4*)(SV + c0);
  union { short8 s; unsigned short u[8]; } lo, hi;
#pragma unroll
  for (int q = 0; q < 2; ++q) {
    float4 a = X4[2 * q], b = X4[2 * q + 1];
    float4 sa = SV4[2 * q], sb = SV4[2 * q + 1];
    unsigned short* o = q ? hi.u : lo.u;
    o[0] = f2bf(a.x * sa.x); o[1] = f2bf(a.y * sa.y);
    o[2] = f2bf(a.z * sa.z); o[3] = f2bf(a.w * sa.w);
    o[4] = f2bf(b.x * sb.x); o[5] = f2bf(b.y * sb.y);
    o[6] = f2bf(b.z * sb.z); o[7] = f2bf(b.w * sb.w);
  }
  short8* Zp = (short8*)(Z + idx);
  Zp[0] = lo.s;
  Zp[1] = hi.s;
}

// ---------------------------------------------------------------------------
// Kernel 2: Wa[i][:] = FHT_4096(codebook-decode(Qidxs[i][:])) / 64, bf16.
// ---------------------------------------------------------------------------
__global__ __launch_bounds__(256) void decode_rowfht_kernel(const int* __restrict__ Q,
                                                            const float* __restrict__ cb,
                                                            unsigned short* __restrict__ Wa) {
  __shared__ float tmp[4096];
  const int row = blockIdx.x;
  const int t = threadIdx.x;
  const int lane = t & 63;
  float v[16];
  int2 qi = *(const int2*)&Q[(size_t)row * 512 + 2 * t];
  {
    const float4* c0 = (const float4*)(cb + (size_t)qi.x * 8);
    const float4* c1 = (const float4*)(cb + (size_t)qi.y * 8);
    float4 p0 = c0[0], p1 = c0[1], p2 = c1[0], p3 = c1[1];
    v[0] = p0.x;  v[1] = p0.y;  v[2] = p0.z;  v[3] = p0.w;
    v[4] = p1.x;  v[5] = p1.y;  v[6] = p1.z;  v[7] = p1.w;
    v[8] = p2.x;  v[9] = p2.y;  v[10] = p2.z; v[11] = p2.w;
    v[12] = p3.x; v[13] = p3.y; v[14] = p3.z; v[15] = p3.w;
  }
  H16_REGS(v)
#pragma unroll
  for (int d = 1; d < 64; d <<= 1) {
#pragma unroll
    for (int j = 0; j < 16; ++j) {
      float p_ = __shfl_xor(v[j], d, 64);
      v[j] = (lane & d) ? (p_ - v[j]) : (v[j] + p_);
    }
  }
#pragma unroll
  for (int dd = 0; dd < 2; ++dd) {
    const int d = 64 << dd;
    if (dd) __syncthreads();
#pragma unroll
    for (int j = 0; j < 16; ++j) tmp[j * 256 + t] = v[j];
    __syncthreads();
#pragma unroll
    for (int j = 0; j < 16; ++j) {
      float p_ = tmp[j * 256 + (t ^ d)];
      v[j] = (t & d) ? (p_ - v[j]) : (v[j] + p_);
    }
  }
  union { short8 s; unsigned short u[8]; } lo, hi;
#pragma unroll
  for (int j = 0; j < 8; ++j) {
    lo.u[j] = f2bf(v[j] * (1.0f / 64.0f));
    hi.u[j] = f2bf(v[8 + j] * (1.0f / 64.0f));
  }
  short8* Wp = (short8*)(Wa + (size_t)row * 4096 + t * 16);
  Wp[0] = lo.s;
  Wp[1] = hi.s;
}

// ---------------------------------------------------------------------------
// Kernels 3a/3b: column-FHT of W (over row index), pass0 = row-bits 0-5,
// pass1 = row-bits 6-11 (applies SU[row]*Wscale/8; pass0 applies 1/8).
// Block = 64 rows x 256 cols, 256 threads; thread = 16 rows x 4 cols.
// ---------------------------------------------------------------------------
template <int PASS>
__global__ __launch_bounds__(256) void fht_wcol_kernel(const unsigned short* __restrict__ Win,
                                                       unsigned short* __restrict__ Wout,
                                                       const float* __restrict__ SU,
                                                       const float* __restrict__ Wscale) {
  __shared__ float tmp[64 * 256];   // 64 KB
  const int rg = blockIdx.x >> 4;
  const int cg = blockIdx.x & 15;
  const int t = threadIdx.x;
  const int cq = t & 63;
  const int q = t >> 6;
  const int c0 = cg * 256 + cq * 4;
  f32x4 v[16];
#pragma unroll
  for (int j = 0; j < 16; ++j) {
    const int rloc = q * 16 + j;
    const int row = (PASS == 0) ? (rg * 64 + rloc) : (rloc * 64 + rg);
    ushort4v u = *(const ushort4v*)&Win[(size_t)row * 4096 + c0];
    v[j][0] = bf2f(u[0]); v[j][1] = bf2f(u[1]);
    v[j][2] = bf2f(u[2]); v[j][3] = bf2f(u[3]);
  }
#pragma unroll
  for (int d = 1; d < 16; d <<= 1) {
#pragma unroll
    for (int j = 0; j < 16; ++j) {
      if ((j & d) == 0) {
        f32x4 a_ = v[j], b_ = v[j | d];
        v[j] = a_ + b_;
        v[j | d] = a_ - b_;
      }
    }
  }
#pragma unroll
  for (int dd = 0; dd < 2; ++dd) {
    const int d = 16 << dd;
    if (dd) __syncthreads();
#pragma unroll
    for (int j = 0; j < 16; ++j)
      *(f32x4*)&tmp[(q * 16 + j) * 256 + cq * 4] = v[j];
    __syncthreads();
#pragma unroll
    for (int j = 0; j < 16; ++j) {
      const int rloc = q * 16 + j;
      f32x4 p_ = *(const f32x4*)&tmp[(rloc ^ d) * 256 + cq * 4];
      v[j] = (rloc & d) ? (p_ - v[j]) : (v[j] + p_);
    }
  }
  if (PASS == 0) {
#pragma unroll
    for (int j = 0; j < 16; ++j) {
      const int row = rg * 64 + q * 16 + j;
      ushort4v w;
      w[0] = f2bf(v[j][0] * 0.125f); w[1] = f2bf(v[j][1] * 0.125f);
      w[2] = f2bf(v[j][2] * 0.125f); w[3] = f2bf(v[j][3] * 0.125f);
      *(ushort4v*)&Wout[(size_t)row * 4096 + c0] = w;
    }
  } else {
    const float ws = Wscale[0] * 0.125f;
#pragma unroll
    for (int j = 0; j < 16; ++j) {
      const int row = (q * 16 + j) * 64 + rg;
      const float s = SU[row] * ws;
      ushort4v w;
      w[0] = f2bf(v[j][0] * s); w[1] = f2bf(v[j][1] * s);
      w[2] = f2bf(v[j][2] * s); w[3] = f2bf(v[j][3] * s);
      *(ushort4v*)&Wout[(size_t)row * 4096 + c0] = w;
    }
  }
}

// ---------------------------------------------------------------------------
// Kernel 4: C[8192][4096] f32 = Z @ W5^T — r5-exact 8-phase K-loop (frozen).
// Staging per tile: P1: A0, P2: B0, P3: A1, P4: B1 (2 gload_lds each).
// Waits: vmcnt(4) @P2-mid, vmcnt(4) @P4-end. XOR swizzle (0 conflicts, r3).
// Epilogue: per-mf LDS transpose (32 rows x 256 cols, stride 260) ->
// float4 C stores: each store instr = 4 rows x 256B contiguous (full lines).
// ---------------------------------------------------------------------------
#define MFMA1(mi, ni, av, bv) \
  acc[mi][ni] = __builtin_amdgcn_mfma_f32_16x16x32_bf16(av, bv, acc[mi][ni], 0, 0, 0)

#define MFMA16(MB, a0_, a1_, a2_, a3_, bx0, bx1, bx2, bx3) do {           \
  MFMA1(MB + 0, 0, a0_, bx0); MFMA1(MB + 0, 1, a0_, bx1);                 \
  MFMA1(MB + 0, 2, a0_, bx2); MFMA1(MB + 0, 3, a0_, bx3);                 \
  MFMA1(MB + 1, 0, a1_, bx0); MFMA1(MB + 1, 1, a1_, bx1);                 \
  MFMA1(MB + 1, 2, a1_, bx2); MFMA1(MB + 1, 3, a1_, bx3);                 \
  MFMA1(MB + 2, 0, a2_, bx0); MFMA1(MB + 2, 1, a2_, bx1);                 \
  MFMA1(MB + 2, 2, a2_, bx2); MFMA1(MB + 2, 3, a2_, bx3);                 \
  MFMA1(MB + 3, 0, a3_, bx0); MFMA1(MB + 3, 1, a3_, bx1);                 \
  MFMA1(MB + 3, 2, a3_, bx2); MFMA1(MB + 3, 3, a3_, bx3);                 \
} while (0)

#define RD_A4(r0, r1, r2, r3, BC, KS, MB) do {                            \
  r0 = *(const short8*)&sA[BC][KS][wm + (MB + 0) * 16 + fr][qc];          \
  r1 = *(const short8*)&sA[BC][KS][wm + (MB + 1) * 16 + fr][qc];          \
  r2 = *(const short8*)&sA[BC][KS][wm + (MB + 2) * 16 + fr][qc];          \
  r3 = *(const short8*)&sA[BC][KS][wm + (MB + 3) * 16 + fr][qc];          \
} while (0)

#define RD_B4(r0, r1, r2, r3, BC, KS) do {                                \
  r0 = *(const short8*)&sB[BC][KS][wn + 0 * 16 + fr][qc];                 \
  r1 = *(const short8*)&sB[BC][KS][wn + 1 * 16 + fr][qc];                 \
  r2 = *(const short8*)&sB[BC][KS][wn + 2 * 16 + fr][qc];                 \
  r3 = *(const short8*)&sB[BC][KS][wn + 3 * 16 + fr][qc];                 \
} while (0)

#define STAGE_A(BB, H, KTN) do {                                          \
  const unsigned short* gp_ = Ag + (KTN) * 64 + (H) * 32;                 \
  gload16(gp_, (unsigned short*)&sA[BB][H][0][0] + d0);                   \
  gload16(gp_ + (size_t)128 * 4096, (unsigned short*)&sA[BB][H][0][0] + d1); \
} while (0)

#define STAGE_B(BB, H, KTN) do {                                          \
  const unsigned short* gp_ = Bg + (KTN) * 64 + (H) * 32;                 \
  gload16(gp_, (unsigned short*)&sB[BB][H][0][0] + d0);                   \
  gload16(gp_ + (size_t)128 * 4096, (unsigned short*)&sB[BB][H][0][0] + d1); \
} while (0)

#define TILE(BC, BN_, KTN, DS, LASTF) do {                                \
  /* P1: top-read own frags (khalf0), prefetch aS1 during MFMA */         \
  RD_A4(aS0_0, aS0_1, aS0_2, aS0_3, BC, 0, 0);                            \
  RD_B4(bA_0, bA_1, bA_2, bA_3, BC, 0);                                   \
  if (DS) { STAGE_A(BN_, 0, KTN); }                                       \
  BAR; LGKM0; SB;                                                         \
  RD_A4(aS1_0, aS1_1, aS1_2, aS1_3, BC, 0, 4); SB;                        \
  PRIO1; MFMA16(0, aS0_0, aS0_1, aS0_2, aS0_3, bA_0, bA_1, bA_2, bA_3);   \
  PRIO0; BAR;                                                             \
  /* P2: vmcnt guards khalf1, then prefetch khalf1 frags */               \
  if (DS) { STAGE_B(BN_, 0, KTN); }                                       \
  BAR; LGKM0; SB;                                                         \
  if (LASTF) { WAIT_VM0; } else { WAIT_VM4; }                             \
  RD_A4(aS0_0, aS0_1, aS0_2, aS0_3, BC, 1, 0);                            \
  RD_B4(bB_0, bB_1, bB_2, bB_3, BC, 1); SB;                               \
  PRIO1; MFMA16(4, aS1_0, aS1_1, aS1_2, aS1_3, bA_0, bA_1, bA_2, bA_3);   \
  PRIO0; BAR;                                                             \
  /* P3: prefetch aS1 (khalf1 mb4-7) */                                   \
  if (DS) { STAGE_A(BN_, 1, KTN); }                                       \
  BAR; LGKM0; SB;                                                         \
  RD_A4(aS1_0, aS1_1, aS1_2, aS1_3, BC, 1, 4); SB;                        \
  PRIO1; MFMA16(0, aS0_0, aS0_1, aS0_2, aS0_3, bB_0, bB_1, bB_2, bB_3);   \
  PRIO0; BAR;                                                             \
  /* P4: no prefetch (next tile P1 reads after its own guard) */          \
  if (DS) { STAGE_B(BN_, 1, KTN); }                                       \
  BAR; LGKM0; SB;                                                         \
  PRIO1; MFMA16(4, aS1_0, aS1_1, aS1_2, aS1_3, bB_0, bB_1, bB_2, bB_3);   \
  PRIO0;                                                                  \
  if (!(LASTF)) { WAIT_VM4; }                                             \
  BAR;                                                                    \
} while (0)

__global__ __launch_bounds__(512, 2) void gemm_bt_kernel(const unsigned short* __restrict__ A,
                                                         const unsigned short* __restrict__ B,
                                                         float* __restrict__ C) {
  __shared__ unsigned short sA[2][2][256][32];
  __shared__ unsigned short sB[2][2][256][32];

  const int bid = blockIdx.x;                    // 512 blocks = 32 tm x 16 tn
  const int swz = (bid & 7) * 64 + (bid >> 3);   // XCD swizzle (512 % 8 == 0)
  const int tm = swz >> 4;                       // 0..31
  const int tn = swz & 15;                       // 0..15

  const int t = threadIdx.x;
  const int lane = t & 63;
  const int w = t >> 6;
  const int wm = (w >> 2) * 128;                 // wave M offset (2 waves)
  const int wn = (w & 3) * 64;                   // wave N offset (4 waves)
  const int fr = lane & 15;
  // read-side swizzled k-chunk: global chunk g=lane>>4 lives at LDS chunk
  // g ^ ((row>>1)&3); row bits 1-2 == lane bits 1-2 (wm/wn/mb*16 touch bits>=4)
  const int qc = ((lane >> 4) ^ ((lane >> 1) & 3)) * 8;

  // staging: thread t covers LDS row sr=t>>2 (and sr+128), LDS chunk t&3;
  // source global chunk = (t&3) ^ swz(row), swz(row) = (row>>1)&3 = (t>>3)&3.
  const int sr = t >> 2;                         // 0..127
  const int sc = ((t & 3) ^ ((t >> 3) & 3)) * 8; // source k-chunk within half
  const unsigned short* Ag = A + (size_t)(tm * 256 + sr) * 4096 + sc;
  const unsigned short* Bg = B + (size_t)(tn * 256 + sr) * 4096 + sc;
  const int d0 = t * 8;                          // dest elem offset, load 0
  const int d1 = (512 + t) * 8;                  // dest elem offset, load 1

  f32x4 acc[8][4];
#pragma unroll
  for (int m = 0; m < 8; ++m)
#pragma unroll
    for (int n = 0; n < 4; ++n) {
      f32x4 z = {0.f, 0.f, 0.f, 0.f};
      acc[m][n] = z;
    }
  short8 aS0_0, aS0_1, aS0_2, aS0_3;
  short8 aS1_0, aS1_1, aS1_2, aS1_3;
  short8 bA_0, bA_1, bA_2, bA_3;
  short8 bB_0, bB_1, bB_2, bB_3;

  // prologue: stage tile 0 (A0,B0,A1,B1 = 8 loads); need A0,B0 -> vmcnt(4)
  STAGE_A(0, 0, 0); STAGE_B(0, 0, 0); STAGE_A(0, 1, 0); STAGE_B(0, 1, 0);
  WAIT_VM4;
  BAR;

  for (int k2 = 0; k2 < 31; ++k2) {
    TILE(0, 1, 2 * k2 + 1, 1, 0);
    TILE(1, 0, 2 * k2 + 2, 1, 0);
  }
  TILE(0, 1, 63, 1, 0);
  TILE(1, 0, 64, 0, 1);

  // -------------------------------------------------------------------------
  // Epilogue: per-mf LDS transpose -> float4 stores.
  // LDS view: 32 rows x 256 cols, row stride 260 (pad 4) = 33.3 KB in dead sA.
  // Write: lds[(lr_w+j)*260 + lc_w + nf*16] = acc  (rows: Mhalf*16+(lane>>4)*4+j,
  //        cols: (w&3)*64 + nf*16 + fr) — 2-way lane bank alias = free.
  // Read: thread t -> local row t>>4, col quad t&15; 4x float4 = 16 floats.
  // Global: wave store instr covers 4 rows x 256B contiguous = full lines.
  // -------------------------------------------------------------------------
  {
    float* lds = (float*)&sA[0][0][0][0];        // dead after K-loop; 33.3 KB
    const int lr_w = (w >> 2) * 16 + (lane >> 4) * 4;
    const int lc_w = (w & 3) * 64 + fr;
    const int rrow = t >> 4;                     // 0..31
    const int rcq = t & 15;                      // 0..15
#pragma unroll
    for (int mf = 0; mf < 8; ++mf) {
      BAR;                                       // prev chunk reads done
#pragma unroll
      for (int nf = 0; nf < 4; ++nf)
#pragma unroll
        for (int j = 0; j < 4; ++j)
          lds[(lr_w + j) * 260 + lc_w + nf * 16] = acc[mf][nf][j];
      BAR;
      const size_t grow = (size_t)tm * 256 + ((rrow & 16) ? 128 : 0) + mf * 16 + (rrow & 15);
      f32x4* Cp = (f32x4*)(C + grow * 4096 + tn * 256 + rcq * 16);
      const float* lp = &lds[rrow * 260 + rcq * 16];
#pragma unroll
      for (int k4 = 0; k4 < 4; ++k4) Cp[k4] = *(const f32x4*)(lp + k4 * 4);
    }
  }
}

// ---------------------------------------------------------------------------
extern "C" void kernel_launch(void* const* d_in, const int* in_sizes, int n_in,
                              void* d_out, int out_size, void* d_ws, size_t ws_size,
                              hipStream_t stream) {
  const float* x      = (const float*)d_in[0];
  const int*   Qidxs  = (const int*)d_in[1];
  const float* SU     = (const float*)d_in[2];
  const float* SV     = (const float*)d_in[3];
  const float* Wscale = (const float*)d_in[4];
  const float* cb     = (const float*)d_in[5];
  float* out = (float*)d_out;

  unsigned short* Z  = (unsigned short*)d_ws;                                      // 64 MB
  unsigned short* Wa = (unsigned short*)((char*)d_ws + (size_t)64 * 1024 * 1024);  // 32 MB
  unsigned short* Wb = (unsigned short*)((char*)d_ws + (size_t)96 * 1024 * 1024);  // 32 MB

  zconv_kernel<<<8192, 256, 0, stream>>>(x, SV, Z);
  decode_rowfht_kernel<<<4096, 256, 0, stream>>>(Qidxs, cb, Wa);
  fht_wcol_kernel<0><<<1024, 256, 0, stream>>>(Wa, Wb, SU, Wscale);
  fht_wcol_kernel<1><<<1024, 256, 0, stream>>>(Wb, Wa, SU, Wscale);
  gemm_bt_kernel<<<512, 512, 0, stream>>>(Z, Wa, out);
}

// Round 15
// 349.513 us; speedup vs baseline: 1.0746x; 1.0746x over previous
//
#include <hip/hip_runtime.h>
#include <hip/hip_bf16.h>

// ---------------------------------------------------------------------------
// E8 RHT Linear:  y = SU * FHT( FHT(SV * x) @ Wr^T * Wscale )
// Identity used:  y = (SV*x) @ W5^T,  W5 = diag(SU*Wscale) * (H Wr H)/4096
// GEMM: r5/r9-exact K-loop (frozen: 256x256, BK=64, 8 waves, 8-phase
// counted-vmcnt, 16x16x32 MFMA, 0 bank conflicts) + scalar C stores (nt).
// r15 = r12-exact consolidation (measured best: 348.7 us).
// ---------------------------------------------------------------------------

using short8   = __attribute__((ext_vector_type(8))) short;
using f32x4    = __attribute__((ext_vector_type(4))) float;
using ushort4v = __attribute__((ext_vector_type(4))) unsigned short;

#define AS1 __attribute__((address_space(1)))
#define AS3 __attribute__((address_space(3)))

__device__ __forceinline__ unsigned short f2bf(float f) {
  unsigned int u = __float_as_uint(f);
  unsigned int r = (u + 0x7fffu + ((u >> 16) & 1u)) >> 16;
  return (unsigned short)r;
}

__device__ __forceinline__ float bf2f(unsigned short u) {
  return __uint_as_float((unsigned int)u << 16);
}

__device__ __forceinline__ void gload16(const void* g, void* l) {
  __builtin_amdgcn_global_load_lds((const AS1 void*)g, (AS3 void*)l, 16, 0, 0);
}

#define WAIT_VM4 asm volatile("s_waitcnt vmcnt(4)" ::: "memory")
#define WAIT_VM0 asm volatile("s_waitcnt vmcnt(0)" ::: "memory")
#define LGKM0    asm volatile("s_waitcnt lgkmcnt(0)" ::: "memory")
#define SB       __builtin_amdgcn_sched_barrier(0)
#define BAR      __builtin_amdgcn_s_barrier()
#define PRIO1    __builtin_amdgcn_s_setprio(1)
#define PRIO0    __builtin_amdgcn_s_setprio(0)

// H16 butterflies over register index j (elem distance 1,2,4,8)
#define H16_REGS(v)                                                       \
  _Pragma("unroll")                                                       \
  for (int d = 1; d < 16; d <<= 1) {                                      \
    _Pragma("unroll")                                                     \
    for (int j = 0; j < 16; ++j) {                                        \
      if ((j & d) == 0) {                                                 \
        float a_ = v[j], b_ = v[j | d];                                   \
        v[j] = a_ + b_;                                                   \
        v[j | d] = a_ - b_;                                               \
      }                                                                   \
    }                                                                     \
  }

// ---------------------------------------------------------------------------
// Kernel 1: z = bf16(SV * x), pure elementwise. 16 elems/thread.
// ---------------------------------------------------------------------------
__global__ __launch_bounds__(256) void zconv_kernel(const float* __restrict__ X,
                                                    const float* __restrict__ SV,
                                                    unsigned short* __restrict__ Z) {
  const size_t idx = ((size_t)blockIdx.x * 256 + threadIdx.x) * 16;
  const int c0 = (int)(idx & 4095);
  const float4* X4 = (const float4*)(X + idx);
  const float4* SV4 = (const float4*)(SV + c0);
  union { short8 s; unsigned short u[8]; } lo, hi;
#pragma unroll
  for (int q = 0; q < 2; ++q) {
    float4 a = X4[2 * q], b = X4[2 * q + 1];
    float4 sa = SV4[2 * q], sb = SV4[2 * q + 1];
    unsigned short* o = q ? hi.u : lo.u;
    o[0] = f2bf(a.x * sa.x); o[1] = f2bf(a.y * sa.y);
    o[2] = f2bf(a.z * sa.z); o[3] = f2bf(a.w * sa.w);
    o[4] = f2bf(b.x * sb.x); o[5] = f2bf(b.y * sb.y);
    o[6] = f2bf(b.z * sb.z); o[7] = f2bf(b.w * sb.w);
  }
  short8* Zp = (short8*)(Z + idx);
  Zp[0] = lo.s;
  Zp[1] = hi.s;
}

// ---------------------------------------------------------------------------
// Kernel 2: Wa[i][:] = FHT_4096(codebook-decode(Qidxs[i][:])) / 64, bf16.
// ---------------------------------------------------------------------------
__global__ __launch_bounds__(256) void decode_rowfht_kernel(const int* __restrict__ Q,
                                                            const float* __restrict__ cb,
                                                            unsigned short* __restrict__ Wa) {
  __shared__ float tmp[4096];
  const int row = blockIdx.x;
  const int t = threadIdx.x;
  const int lane = t & 63;
  float v[16];
  int2 qi = *(const int2*)&Q[(size_t)row * 512 + 2 * t];
  {
    const float4* c0 = (const float4*)(cb + (size_t)qi.x * 8);
    const float4* c1 = (const float4*)(cb + (size_t)qi.y * 8);
    float4 p0 = c0[0], p1 = c0[1], p2 = c1[0], p3 = c1[1];
    v[0] = p0.x;  v[1] = p0.y;  v[2] = p0.z;  v[3] = p0.w;
    v[4] = p1.x;  v[5] = p1.y;  v[6] = p1.z;  v[7] = p1.w;
    v[8] = p2.x;  v[9] = p2.y;  v[10] = p2.z; v[11] = p2.w;
    v[12] = p3.x; v[13] = p3.y; v[14] = p3.z; v[15] = p3.w;
  }
  H16_REGS(v)
#pragma unroll
  for (int d = 1; d < 64; d <<= 1) {
#pragma unroll
    for (int j = 0; j < 16; ++j) {
      float p_ = __shfl_xor(v[j], d, 64);
      v[j] = (lane & d) ? (p_ - v[j]) : (v[j] + p_);
    }
  }
#pragma unroll
  for (int dd = 0; dd < 2; ++dd) {
    const int d = 64 << dd;
    if (dd) __syncthreads();
#pragma unroll
    for (int j = 0; j < 16; ++j) tmp[j * 256 + t] = v[j];
    __syncthreads();
#pragma unroll
    for (int j = 0; j < 16; ++j) {
      float p_ = tmp[j * 256 + (t ^ d)];
      v[j] = (t & d) ? (p_ - v[j]) : (v[j] + p_);
    }
  }
  union { short8 s; unsigned short u[8]; } lo, hi;
#pragma unroll
  for (int j = 0; j < 8; ++j) {
    lo.u[j] = f2bf(v[j] * (1.0f / 64.0f));
    hi.u[j] = f2bf(v[8 + j] * (1.0f / 64.0f));
  }
  short8* Wp = (short8*)(Wa + (size_t)row * 4096 + t * 16);
  Wp[0] = lo.s;
  Wp[1] = hi.s;
}

// ---------------------------------------------------------------------------
// Kernels 3a/3b: column-FHT of W (over row index), pass0 = row-bits 0-5,
// pass1 = row-bits 6-11 (applies SU[row]*Wscale/8; pass0 applies 1/8).
// Block = 64 rows x 256 cols, 256 threads; thread = 16 rows x 4 cols.
// ---------------------------------------------------------------------------
template <int PASS>
__global__ __launch_bounds__(256) void fht_wcol_kernel(const unsigned short* __restrict__ Win,
                                                       unsigned short* __restrict__ Wout,
                                                       const float* __restrict__ SU,
                                                       const float* __restrict__ Wscale) {
  __shared__ float tmp[64 * 256];   // 64 KB
  const int rg = blockIdx.x >> 4;
  const int cg = blockIdx.x & 15;
  const int t = threadIdx.x;
  const int cq = t & 63;
  const int q = t >> 6;
  const int c0 = cg * 256 + cq * 4;
  f32x4 v[16];
#pragma unroll
  for (int j = 0; j < 16; ++j) {
    const int rloc = q * 16 + j;
    const int row = (PASS == 0) ? (rg * 64 + rloc) : (rloc * 64 + rg);
    ushort4v u = *(const ushort4v*)&Win[(size_t)row * 4096 + c0];
    v[j][0] = bf2f(u[0]); v[j][1] = bf2f(u[1]);
    v[j][2] = bf2f(u[2]); v[j][3] = bf2f(u[3]);
  }
#pragma unroll
  for (int d = 1; d < 16; d <<= 1) {
#pragma unroll
    for (int j = 0; j < 16; ++j) {
      if ((j & d) == 0) {
        f32x4 a_ = v[j], b_ = v[j | d];
        v[j] = a_ + b_;
        v[j | d] = a_ - b_;
      }
    }
  }
#pragma unroll
  for (int dd = 0; dd < 2; ++dd) {
    const int d = 16 << dd;
    if (dd) __syncthreads();
#pragma unroll
    for (int j = 0; j < 16; ++j)
      *(f32x4*)&tmp[(q * 16 + j) * 256 + cq * 4] = v[j];
    __syncthreads();
#pragma unroll
    for (int j = 0; j < 16; ++j) {
      const int rloc = q * 16 + j;
      f32x4 p_ = *(const f32x4*)&tmp[(rloc ^ d) * 256 + cq * 4];
      v[j] = (rloc & d) ? (p_ - v[j]) : (v[j] + p_);
    }
  }
  if (PASS == 0) {
#pragma unroll
    for (int j = 0; j < 16; ++j) {
      const int row = rg * 64 + q * 16 + j;
      ushort4v w;
      w[0] = f2bf(v[j][0] * 0.125f); w[1] = f2bf(v[j][1] * 0.125f);
      w[2] = f2bf(v[j][2] * 0.125f); w[3] = f2bf(v[j][3] * 0.125f);
      *(ushort4v*)&Wout[(size_t)row * 4096 + c0] = w;
    }
  } else {
    const float ws = Wscale[0] * 0.125f;
#pragma unroll
    for (int j = 0; j < 16; ++j) {
      const int row = (q * 16 + j) * 64 + rg;
      const float s = SU[row] * ws;
      ushort4v w;
      w[0] = f2bf(v[j][0] * s); w[1] = f2bf(v[j][1] * s);
      w[2] = f2bf(v[j][2] * s); w[3] = f2bf(v[j][3] * s);
      *(ushort4v*)&Wout[(size_t)row * 4096 + c0] = w;
    }
  }
}

// ---------------------------------------------------------------------------
// Kernel 4: C[8192][4096] f32 = Z @ W5^T — r5-exact 8-phase K-loop (frozen).
// Staging per tile: P1: A0, P2: B0, P3: A1, P4: B1 (2 gload_lds each).
// Waits: vmcnt(4) @P2-mid, vmcnt(4) @P4-end. XOR swizzle (0 conflicts, r3).
// Epilogue: scalar nontemporal stores (r12-exact, measured best).
// ---------------------------------------------------------------------------
#define MFMA1(mi, ni, av, bv) \
  acc[mi][ni] = __builtin_amdgcn_mfma_f32_16x16x32_bf16(av, bv, acc[mi][ni], 0, 0, 0)

#define MFMA16(MB, a0_, a1_, a2_, a3_, bx0, bx1, bx2, bx3) do {           \
  MFMA1(MB + 0, 0, a0_, bx0); MFMA1(MB + 0, 1, a0_, bx1);                 \
  MFMA1(MB + 0, 2, a0_, bx2); MFMA1(MB + 0, 3, a0_, bx3);                 \
  MFMA1(MB + 1, 0, a1_, bx0); MFMA1(MB + 1, 1, a1_, bx1);                 \
  MFMA1(MB + 1, 2, a1_, bx2); MFMA1(MB + 1, 3, a1_, bx3);                 \
  MFMA1(MB + 2, 0, a2_, bx0); MFMA1(MB + 2, 1, a2_, bx1);                 \
  MFMA1(MB + 2, 2, a2_, bx2); MFMA1(MB + 2, 3, a2_, bx3);                 \
  MFMA1(MB + 3, 0, a3_, bx0); MFMA1(MB + 3, 1, a3_, bx1);                 \
  MFMA1(MB + 3, 2, a3_, bx2); MFMA1(MB + 3, 3, a3_, bx3);                 \
} while (0)

#define RD_A4(r0, r1, r2, r3, BC, KS, MB) do {                            \
  r0 = *(const short8*)&sA[BC][KS][wm + (MB + 0) * 16 + fr][qc];          \
  r1 = *(const short8*)&sA[BC][KS][wm + (MB + 1) * 16 + fr][qc];          \
  r2 = *(const short8*)&sA[BC][KS][wm + (MB + 2) * 16 + fr][qc];          \
  r3 = *(const short8*)&sA[BC][KS][wm + (MB + 3) * 16 + fr][qc];          \
} while (0)

#define RD_B4(r0, r1, r2, r3, BC, KS) do {                                \
  r0 = *(const short8*)&sB[BC][KS][wn + 0 * 16 + fr][qc];                 \
  r1 = *(const short8*)&sB[BC][KS][wn + 1 * 16 + fr][qc];                 \
  r2 = *(const short8*)&sB[BC][KS][wn + 2 * 16 + fr][qc];                 \
  r3 = *(const short8*)&sB[BC][KS][wn + 3 * 16 + fr][qc];                 \
} while (0)

#define STAGE_A(BB, H, KTN) do {                                          \
  const unsigned short* gp_ = Ag + (KTN) * 64 + (H) * 32;                 \
  gload16(gp_, (unsigned short*)&sA[BB][H][0][0] + d0);                   \
  gload16(gp_ + (size_t)128 * 4096, (unsigned short*)&sA[BB][H][0][0] + d1); \
} while (0)

#define STAGE_B(BB, H, KTN) do {                                          \
  const unsigned short* gp_ = Bg + (KTN) * 64 + (H) * 32;                 \
  gload16(gp_, (unsigned short*)&sB[BB][H][0][0] + d0);                   \
  gload16(gp_ + (size_t)128 * 4096, (unsigned short*)&sB[BB][H][0][0] + d1); \
} while (0)

#define TILE(BC, BN_, KTN, DS, LASTF) do {                                \
  /* P1: top-read own frags (khalf0), prefetch aS1 during MFMA */         \
  RD_A4(aS0_0, aS0_1, aS0_2, aS0_3, BC, 0, 0);                            \
  RD_B4(bA_0, bA_1, bA_2, bA_3, BC, 0);                                   \
  if (DS) { STAGE_A(BN_, 0, KTN); }                                       \
  BAR; LGKM0; SB;                                                         \
  RD_A4(aS1_0, aS1_1, aS1_2, aS1_3, BC, 0, 4); SB;                        \
  PRIO1; MFMA16(0, aS0_0, aS0_1, aS0_2, aS0_3, bA_0, bA_1, bA_2, bA_3);   \
  PRIO0; BAR;                                                             \
  /* P2: vmcnt guards khalf1, then prefetch khalf1 frags */               \
  if (DS) { STAGE_B(BN_, 0, KTN); }                                       \
  BAR; LGKM0; SB;                                                         \
  if (LASTF) { WAIT_VM0; } else { WAIT_VM4; }                             \
  RD_A4(aS0_0, aS0_1, aS0_2, aS0_3, BC, 1, 0);                            \
  RD_B4(bB_0, bB_1, bB_2, bB_3, BC, 1); SB;                               \
  PRIO1; MFMA16(4, aS1_0, aS1_1, aS1_2, aS1_3, bA_0, bA_1, bA_2, bA_3);   \
  PRIO0; BAR;                                                             \
  /* P3: prefetch aS1 (khalf1 mb4-7) */                                   \
  if (DS) { STAGE_A(BN_, 1, KTN); }                                       \
  BAR; LGKM0; SB;                                                         \
  RD_A4(aS1_0, aS1_1, aS1_2, aS1_3, BC, 1, 4); SB;                        \
  PRIO1; MFMA16(0, aS0_0, aS0_1, aS0_2, aS0_3, bB_0, bB_1, bB_2, bB_3);   \
  PRIO0; BAR;                                                             \
  /* P4: no prefetch (next tile P1 reads after its own guard) */          \
  if (DS) { STAGE_B(BN_, 1, KTN); }                                       \
  BAR; LGKM0; SB;                                                         \
  PRIO1; MFMA16(4, aS1_0, aS1_1, aS1_2, aS1_3, bB_0, bB_1, bB_2, bB_3);   \
  PRIO0;                                                                  \
  if (!(LASTF)) { WAIT_VM4; }                                             \
  BAR;                                                                    \
} while (0)

__global__ __launch_bounds__(512, 2) void gemm_bt_kernel(const unsigned short* __restrict__ A,
                                                         const unsigned short* __restrict__ B,
                                                         float* __restrict__ C) {
  __shared__ unsigned short sA[2][2][256][32];
  __shared__ unsigned short sB[2][2][256][32];

  const int bid = blockIdx.x;                    // 512 blocks = 32 tm x 16 tn
  const int swz = (bid & 7) * 64 + (bid >> 3);   // XCD swizzle (512 % 8 == 0)
  const int tm = swz >> 4;                       // 0..31
  const int tn = swz & 15;                       // 0..15

  const int t = threadIdx.x;
  const int lane = t & 63;
  const int w = t >> 6;
  const int wm = (w >> 2) * 128;                 // wave M offset (2 waves)
  const int wn = (w & 3) * 64;                   // wave N offset (4 waves)
  const int fr = lane & 15;
  // read-side swizzled k-chunk: global chunk g=lane>>4 lives at LDS chunk
  // g ^ ((row>>1)&3); row bits 1-2 == lane bits 1-2 (wm/wn/mb*16 touch bits>=4)
  const int qc = ((lane >> 4) ^ ((lane >> 1) & 3)) * 8;

  // staging: thread t covers LDS row sr=t>>2 (and sr+128), LDS chunk t&3;
  // source global chunk = (t&3) ^ swz(row), swz(row) = (row>>1)&3 = (t>>3)&3.
  const int sr = t >> 2;                         // 0..127
  const int sc = ((t & 3) ^ ((t >> 3) & 3)) * 8; // source k-chunk within half
  const unsigned short* Ag = A + (size_t)(tm * 256 + sr) * 4096 + sc;
  const unsigned short* Bg = B + (size_t)(tn * 256 + sr) * 4096 + sc;
  const int d0 = t * 8;                          // dest elem offset, load 0
  const int d1 = (512 + t) * 8;                  // dest elem offset, load 1

  f32x4 acc[8][4];
#pragma unroll
  for (int m = 0; m < 8; ++m)
#pragma unroll
    for (int n = 0; n < 4; ++n) {
      f32x4 z = {0.f, 0.f, 0.f, 0.f};
      acc[m][n] = z;
    }
  short8 aS0_0, aS0_1, aS0_2, aS0_3;
  short8 aS1_0, aS1_1, aS1_2, aS1_3;
  short8 bA_0, bA_1, bA_2, bA_3;
  short8 bB_0, bB_1, bB_2, bB_3;

  // prologue: stage tile 0 (A0,B0,A1,B1 = 8 loads); need A0,B0 -> vmcnt(4)
  STAGE_A(0, 0, 0); STAGE_B(0, 0, 0); STAGE_A(0, 1, 0); STAGE_B(0, 1, 0);
  WAIT_VM4;
  BAR;

  for (int k2 = 0; k2 < 31; ++k2) {
    TILE(0, 1, 2 * k2 + 1, 1, 0);
    TILE(1, 0, 2 * k2 + 2, 1, 0);
  }
  TILE(0, 1, 63, 1, 0);
  TILE(1, 0, 64, 0, 1);

  // epilogue: C/D layout col = lane&15, row = (lane>>4)*4 + j  (nontemporal)
  const size_t crow0 = (size_t)tm * 256 + wm + (lane >> 4) * 4;
  const int ccol0 = tn * 256 + wn + fr;
#pragma unroll
  for (int mf = 0; mf < 8; ++mf)
#pragma unroll
    for (int j = 0; j < 4; ++j) {
      float* Cp = C + (crow0 + mf * 16 + j) * 4096 + ccol0;
#pragma unroll
      for (int nf = 0; nf < 4; ++nf)
        __builtin_nontemporal_store(acc[mf][nf][j], Cp + nf * 16);
    }
}

// ---------------------------------------------------------------------------
extern "C" void kernel_launch(void* const* d_in, const int* in_sizes, int n_in,
                              void* d_out, int out_size, void* d_ws, size_t ws_size,
                              hipStream_t stream) {
  const float* x      = (const float*)d_in[0];
  const int*   Qidxs  = (const int*)d_in[1];
  const float* SU     = (const float*)d_in[2];
  const float* SV     = (const float*)d_in[3];
  const float* Wscale = (const float*)d_in[4];
  const float* cb     = (const float*)d_in[5];
  float* out = (float*)d_out;

  unsigned short* Z  = (unsigned short*)d_ws;                                      // 64 MB
  unsigned short* Wa = (unsigned short*)((char*)d_ws + (size_t)64 * 1024 * 1024);  // 32 MB
  unsigned short* Wb = (unsigned short*)((char*)d_ws + (size_t)96 * 1024 * 1024);  // 32 MB

  zconv_kernel<<<8192, 256, 0, stream>>>(x, SV, Z);
  decode_rowfht_kernel<<<4096, 256, 0, stream>>>(Qidxs, cb, Wa);
  fht_wcol_kernel<0><<<1024, 256, 0, stream>>>(Wa, Wb, SU, Wscale);
  fht_wcol_kernel<1><<<1024, 256, 0, stream>>>(Wb, Wa, SU, Wscale);
  gemm_bt_kernel<<<512, 512, 0, stream>>>(Z, Wa, out);
}

// Round 16
// 343.873 us; speedup vs baseline: 1.0922x; 1.0164x over previous
//
#include <hip/hip_runtime.h>
#include <hip/hip_bf16.h>

// ---------------------------------------------------------------------------
// E8 RHT Linear:  y = SU * FHT( FHT(SV * x) @ Wr^T * Wscale )
// Identity used:  y = (SV*x) @ W5^T,  W5 = diag(SU*Wscale) * (H Wr H)/4096
// GEMM: r5/r9-exact K-loop (frozen: 256x256, BK=64, 8 waves, 8-phase
// counted-vmcnt, 16x16x32 MFMA, 0 bank conflicts) + scalar nt C stores.
// r16: fuse zconv + decode_rowfht (independent) into one dispatch.
// ---------------------------------------------------------------------------

using short8   = __attribute__((ext_vector_type(8))) short;
using f32x4    = __attribute__((ext_vector_type(4))) float;
using ushort4v = __attribute__((ext_vector_type(4))) unsigned short;

#define AS1 __attribute__((address_space(1)))
#define AS3 __attribute__((address_space(3)))

__device__ __forceinline__ unsigned short f2bf(float f) {
  unsigned int u = __float_as_uint(f);
  unsigned int r = (u + 0x7fffu + ((u >> 16) & 1u)) >> 16;
  return (unsigned short)r;
}

__device__ __forceinline__ float bf2f(unsigned short u) {
  return __uint_as_float((unsigned int)u << 16);
}

__device__ __forceinline__ void gload16(const void* g, void* l) {
  __builtin_amdgcn_global_load_lds((const AS1 void*)g, (AS3 void*)l, 16, 0, 0);
}

#define WAIT_VM4 asm volatile("s_waitcnt vmcnt(4)" ::: "memory")
#define WAIT_VM0 asm volatile("s_waitcnt vmcnt(0)" ::: "memory")
#define LGKM0    asm volatile("s_waitcnt lgkmcnt(0)" ::: "memory")
#define SB       __builtin_amdgcn_sched_barrier(0)
#define BAR      __builtin_amdgcn_s_barrier()
#define PRIO1    __builtin_amdgcn_s_setprio(1)
#define PRIO0    __builtin_amdgcn_s_setprio(0)

// H16 butterflies over register index j (elem distance 1,2,4,8)
#define H16_REGS(v)                                                       \
  _Pragma("unroll")                                                       \
  for (int d = 1; d < 16; d <<= 1) {                                      \
    _Pragma("unroll")                                                     \
    for (int j = 0; j < 16; ++j) {                                        \
      if ((j & d) == 0) {                                                 \
        float a_ = v[j], b_ = v[j | d];                                   \
        v[j] = a_ + b_;                                                   \
        v[j | d] = a_ - b_;                                               \
      }                                                                   \
    }                                                                     \
  }

// ---------------------------------------------------------------------------
// Kernel 1 (fused): blocks [0,8192): z = bf16(SV*x) elementwise;
// blocks [8192,12288): Wa[row] = FHT_4096(decode(Qidxs[row]))/64.
// Independent data; each block takes exactly one branch (syncthreads in the
// decode branch is block-uniform). 16 KB LDS (decode path only).
// ---------------------------------------------------------------------------
__global__ __launch_bounds__(256) void zconv_decode_kernel(const float* __restrict__ X,
                                                           const float* __restrict__ SV,
                                                           unsigned short* __restrict__ Z,
                                                           const int* __restrict__ Q,
                                                           const float* __restrict__ cb,
                                                           unsigned short* __restrict__ Wa) {
  __shared__ float tmp[4096];
  const int t = threadIdx.x;
  if (blockIdx.x < 8192) {
    // ---- zconv ----
    const size_t idx = ((size_t)blockIdx.x * 256 + t) * 16;
    const int c0 = (int)(idx & 4095);
    const float4* X4 = (const float4*)(X + idx);
    const float4* SV4 = (const float4*)(SV + c0);
    union { short8 s; unsigned short u[8]; } lo, hi;
#pragma unroll
    for (int q = 0; q < 2; ++q) {
      float4 a = X4[2 * q], b = X4[2 * q + 1];
      float4 sa = SV4[2 * q], sb = SV4[2 * q + 1];
      unsigned short* o = q ? hi.u : lo.u;
      o[0] = f2bf(a.x * sa.x); o[1] = f2bf(a.y * sa.y);
      o[2] = f2bf(a.z * sa.z); o[3] = f2bf(a.w * sa.w);
      o[4] = f2bf(b.x * sb.x); o[5] = f2bf(b.y * sb.y);
      o[6] = f2bf(b.z * sb.z); o[7] = f2bf(b.w * sb.w);
    }
    short8* Zp = (short8*)(Z + idx);
    Zp[0] = lo.s;
    Zp[1] = hi.s;
  } else {
    // ---- decode + row FHT ----
    const int row = blockIdx.x - 8192;
    const int lane = t & 63;
    float v[16];
    int2 qi = *(const int2*)&Q[(size_t)row * 512 + 2 * t];
    {
      const float4* c0 = (const float4*)(cb + (size_t)qi.x * 8);
      const float4* c1 = (const float4*)(cb + (size_t)qi.y * 8);
      float4 p0 = c0[0], p1 = c0[1], p2 = c1[0], p3 = c1[1];
      v[0] = p0.x;  v[1] = p0.y;  v[2] = p0.z;  v[3] = p0.w;
      v[4] = p1.x;  v[5] = p1.y;  v[6] = p1.z;  v[7] = p1.w;
      v[8] = p2.x;  v[9] = p2.y;  v[10] = p2.z; v[11] = p2.w;
      v[12] = p3.x; v[13] = p3.y; v[14] = p3.z; v[15] = p3.w;
    }
    H16_REGS(v)
#pragma unroll
    for (int d = 1; d < 64; d <<= 1) {
#pragma unroll
      for (int j = 0; j < 16; ++j) {
        float p_ = __shfl_xor(v[j], d, 64);
        v[j] = (lane & d) ? (p_ - v[j]) : (v[j] + p_);
      }
    }
#pragma unroll
    for (int dd = 0; dd < 2; ++dd) {
      const int d = 64 << dd;
      if (dd) __syncthreads();
#pragma unroll
      for (int j = 0; j < 16; ++j) tmp[j * 256 + t] = v[j];
      __syncthreads();
#pragma unroll
      for (int j = 0; j < 16; ++j) {
        float p_ = tmp[j * 256 + (t ^ d)];
        v[j] = (t & d) ? (p_ - v[j]) : (v[j] + p_);
      }
    }
    union { short8 s; unsigned short u[8]; } lo, hi;
#pragma unroll
    for (int j = 0; j < 8; ++j) {
      lo.u[j] = f2bf(v[j] * (1.0f / 64.0f));
      hi.u[j] = f2bf(v[8 + j] * (1.0f / 64.0f));
    }
    short8* Wp = (short8*)(Wa + (size_t)row * 4096 + t * 16);
    Wp[0] = lo.s;
    Wp[1] = hi.s;
  }
}

// ---------------------------------------------------------------------------
// Kernels 2a/2b: column-FHT of W (over row index), pass0 = row-bits 0-5,
// pass1 = row-bits 6-11 (applies SU[row]*Wscale/8; pass0 applies 1/8).
// Block = 64 rows x 256 cols, 256 threads; thread = 16 rows x 4 cols.
// ---------------------------------------------------------------------------
template <int PASS>
__global__ __launch_bounds__(256) void fht_wcol_kernel(const unsigned short* __restrict__ Win,
                                                       unsigned short* __restrict__ Wout,
                                                       const float* __restrict__ SU,
                                                       const float* __restrict__ Wscale) {
  __shared__ float tmp[64 * 256];   // 64 KB
  const int rg = blockIdx.x >> 4;
  const int cg = blockIdx.x & 15;
  const int t = threadIdx.x;
  const int cq = t & 63;
  const int q = t >> 6;
  const int c0 = cg * 256 + cq * 4;
  f32x4 v[16];
#pragma unroll
  for (int j = 0; j < 16; ++j) {
    const int rloc = q * 16 + j;
    const int row = (PASS == 0) ? (rg * 64 + rloc) : (rloc * 64 + rg);
    ushort4v u = *(const ushort4v*)&Win[(size_t)row * 4096 + c0];
    v[j][0] = bf2f(u[0]); v[j][1] = bf2f(u[1]);
    v[j][2] = bf2f(u[2]); v[j][3] = bf2f(u[3]);
  }
#pragma unroll
  for (int d = 1; d < 16; d <<= 1) {
#pragma unroll
    for (int j = 0; j < 16; ++j) {
      if ((j & d) == 0) {
        f32x4 a_ = v[j], b_ = v[j | d];
        v[j] = a_ + b_;
        v[j | d] = a_ - b_;
      }
    }
  }
#pragma unroll
  for (int dd = 0; dd < 2; ++dd) {
    const int d = 16 << dd;
    if (dd) __syncthreads();
#pragma unroll
    for (int j = 0; j < 16; ++j)
      *(f32x4*)&tmp[(q * 16 + j) * 256 + cq * 4] = v[j];
    __syncthreads();
#pragma unroll
    for (int j = 0; j < 16; ++j) {
      const int rloc = q * 16 + j;
      f32x4 p_ = *(const f32x4*)&tmp[(rloc ^ d) * 256 + cq * 4];
      v[j] = (rloc & d) ? (p_ - v[j]) : (v[j] + p_);
    }
  }
  if (PASS == 0) {
#pragma unroll
    for (int j = 0; j < 16; ++j) {
      const int row = rg * 64 + q * 16 + j;
      ushort4v w;
      w[0] = f2bf(v[j][0] * 0.125f); w[1] = f2bf(v[j][1] * 0.125f);
      w[2] = f2bf(v[j][2] * 0.125f); w[3] = f2bf(v[j][3] * 0.125f);
      *(ushort4v*)&Wout[(size_t)row * 4096 + c0] = w;
    }
  } else {
    const float ws = Wscale[0] * 0.125f;
#pragma unroll
    for (int j = 0; j < 16; ++j) {
      const int row = (q * 16 + j) * 64 + rg;
      const float s = SU[row] * ws;
      ushort4v w;
      w[0] = f2bf(v[j][0] * s); w[1] = f2bf(v[j][1] * s);
      w[2] = f2bf(v[j][2] * s); w[3] = f2bf(v[j][3] * s);
      *(ushort4v*)&Wout[(size_t)row * 4096 + c0] = w;
    }
  }
}

// ---------------------------------------------------------------------------
// Kernel 3: C[8192][4096] f32 = Z @ W5^T — r5-exact 8-phase K-loop (frozen).
// Staging per tile: P1: A0, P2: B0, P3: A1, P4: B1 (2 gload_lds each).
// Waits: vmcnt(4) @P2-mid, vmcnt(4) @P4-end. XOR swizzle (0 conflicts, r3).
// Epilogue: scalar nontemporal stores (r12-exact, measured best).
// ---------------------------------------------------------------------------
#define MFMA1(mi, ni, av, bv) \
  acc[mi][ni] = __builtin_amdgcn_mfma_f32_16x16x32_bf16(av, bv, acc[mi][ni], 0, 0, 0)

#define MFMA16(MB, a0_, a1_, a2_, a3_, bx0, bx1, bx2, bx3) do {           \
  MFMA1(MB + 0, 0, a0_, bx0); MFMA1(MB + 0, 1, a0_, bx1);                 \
  MFMA1(MB + 0, 2, a0_, bx2); MFMA1(MB + 0, 3, a0_, bx3);                 \
  MFMA1(MB + 1, 0, a1_, bx0); MFMA1(MB + 1, 1, a1_, bx1);                 \
  MFMA1(MB + 1, 2, a1_, bx2); MFMA1(MB + 1, 3, a1_, bx3);                 \
  MFMA1(MB + 2, 0, a2_, bx0); MFMA1(MB + 2, 1, a2_, bx1);                 \
  MFMA1(MB + 2, 2, a2_, bx2); MFMA1(MB + 2, 3, a2_, bx3);                 \
  MFMA1(MB + 3, 0, a3_, bx0); MFMA1(MB + 3, 1, a3_, bx1);                 \
  MFMA1(MB + 3, 2, a3_, bx2); MFMA1(MB + 3, 3, a3_, bx3);                 \
} while (0)

#define RD_A4(r0, r1, r2, r3, BC, KS, MB) do {                            \
  r0 = *(const short8*)&sA[BC][KS][wm + (MB + 0) * 16 + fr][qc];          \
  r1 = *(const short8*)&sA[BC][KS][wm + (MB + 1) * 16 + fr][qc];          \
  r2 = *(const short8*)&sA[BC][KS][wm + (MB + 2) * 16 + fr][qc];          \
  r3 = *(const short8*)&sA[BC][KS][wm + (MB + 3) * 16 + fr][qc];          \
} while (0)

#define RD_B4(r0, r1, r2, r3, BC, KS) do {                                \
  r0 = *(const short8*)&sB[BC][KS][wn + 0 * 16 + fr][qc];                 \
  r1 = *(const short8*)&sB[BC][KS][wn + 1 * 16 + fr][qc];                 \
  r2 = *(const short8*)&sB[BC][KS][wn + 2 * 16 + fr][qc];                 \
  r3 = *(const short8*)&sB[BC][KS][wn + 3 * 16 + fr][qc];                 \
} while (0)

#define STAGE_A(BB, H, KTN) do {                                          \
  const unsigned short* gp_ = Ag + (KTN) * 64 + (H) * 32;                 \
  gload16(gp_, (unsigned short*)&sA[BB][H][0][0] + d0);                   \
  gload16(gp_ + (size_t)128 * 4096, (unsigned short*)&sA[BB][H][0][0] + d1); \
} while (0)

#define STAGE_B(BB, H, KTN) do {                                          \
  const unsigned short* gp_ = Bg + (KTN) * 64 + (H) * 32;                 \
  gload16(gp_, (unsigned short*)&sB[BB][H][0][0] + d0);                   \
  gload16(gp_ + (size_t)128 * 4096, (unsigned short*)&sB[BB][H][0][0] + d1); \
} while (0)

#define TILE(BC, BN_, KTN, DS, LASTF) do {                                \
  /* P1: top-read own frags (khalf0), prefetch aS1 during MFMA */         \
  RD_A4(aS0_0, aS0_1, aS0_2, aS0_3, BC, 0, 0);                            \
  RD_B4(bA_0, bA_1, bA_2, bA_3, BC, 0);                                   \
  if (DS) { STAGE_A(BN_, 0, KTN); }                                       \
  BAR; LGKM0; SB;                                                         \
  RD_A4(aS1_0, aS1_1, aS1_2, aS1_3, BC, 0, 4); SB;                        \
  PRIO1; MFMA16(0, aS0_0, aS0_1, aS0_2, aS0_3, bA_0, bA_1, bA_2, bA_3);   \
  PRIO0; BAR;                                                             \
  /* P2: vmcnt guards khalf1, then prefetch khalf1 frags */               \
  if (DS) { STAGE_B(BN_, 0, KTN); }                                       \
  BAR; LGKM0; SB;                                                         \
  if (LASTF) { WAIT_VM0; } else { WAIT_VM4; }                             \
  RD_A4(aS0_0, aS0_1, aS0_2, aS0_3, BC, 1, 0);                            \
  RD_B4(bB_0, bB_1, bB_2, bB_3, BC, 1); SB;                               \
  PRIO1; MFMA16(4, aS1_0, aS1_1, aS1_2, aS1_3, bA_0, bA_1, bA_2, bA_3);   \
  PRIO0; BAR;                                                             \
  /* P3: prefetch aS1 (khalf1 mb4-7) */                                   \
  if (DS) { STAGE_A(BN_, 1, KTN); }                                       \
  BAR; LGKM0; SB;                                                         \
  RD_A4(aS1_0, aS1_1, aS1_2, aS1_3, BC, 1, 4); SB;                        \
  PRIO1; MFMA16(0, aS0_0, aS0_1, aS0_2, aS0_3, bB_0, bB_1, bB_2, bB_3);   \
  PRIO0; BAR;                                                             \
  /* P4: no prefetch (next tile P1 reads after its own guard) */          \
  if (DS) { STAGE_B(BN_, 1, KTN); }                                       \
  BAR; LGKM0; SB;                                                         \
  PRIO1; MFMA16(4, aS1_0, aS1_1, aS1_2, aS1_3, bB_0, bB_1, bB_2, bB_3);   \
  PRIO0;                                                                  \
  if (!(LASTF)) { WAIT_VM4; }                                             \
  BAR;                                                                    \
} while (0)

__global__ __launch_bounds__(512, 2) void gemm_bt_kernel(const unsigned short* __restrict__ A,
                                                         const unsigned short* __restrict__ B,
                                                         float* __restrict__ C) {
  __shared__ unsigned short sA[2][2][256][32];
  __shared__ unsigned short sB[2][2][256][32];

  const int bid = blockIdx.x;                    // 512 blocks = 32 tm x 16 tn
  const int swz = (bid & 7) * 64 + (bid >> 3);   // XCD swizzle (512 % 8 == 0)
  const int tm = swz >> 4;                       // 0..31
  const int tn = swz & 15;                       // 0..15

  const int t = threadIdx.x;
  const int lane = t & 63;
  const int w = t >> 6;
  const int wm = (w >> 2) * 128;                 // wave M offset (2 waves)
  const int wn = (w & 3) * 64;                   // wave N offset (4 waves)
  const int fr = lane & 15;
  // read-side swizzled k-chunk: global chunk g=lane>>4 lives at LDS chunk
  // g ^ ((row>>1)&3); row bits 1-2 == lane bits 1-2 (wm/wn/mb*16 touch bits>=4)
  const int qc = ((lane >> 4) ^ ((lane >> 1) & 3)) * 8;

  // staging: thread t covers LDS row sr=t>>2 (and sr+128), LDS chunk t&3;
  // source global chunk = (t&3) ^ swz(row), swz(row) = (row>>1)&3 = (t>>3)&3.
  const int sr = t >> 2;                         // 0..127
  const int sc = ((t & 3) ^ ((t >> 3) & 3)) * 8; // source k-chunk within half
  const unsigned short* Ag = A + (size_t)(tm * 256 + sr) * 4096 + sc;
  const unsigned short* Bg = B + (size_t)(tn * 256 + sr) * 4096 + sc;
  const int d0 = t * 8;                          // dest elem offset, load 0
  const int d1 = (512 + t) * 8;                  // dest elem offset, load 1

  f32x4 acc[8][4];
#pragma unroll
  for (int m = 0; m < 8; ++m)
#pragma unroll
    for (int n = 0; n < 4; ++n) {
      f32x4 z = {0.f, 0.f, 0.f, 0.f};
      acc[m][n] = z;
    }
  short8 aS0_0, aS0_1, aS0_2, aS0_3;
  short8 aS1_0, aS1_1, aS1_2, aS1_3;
  short8 bA_0, bA_1, bA_2, bA_3;
  short8 bB_0, bB_1, bB_2, bB_3;

  // prologue: stage tile 0 (A0,B0,A1,B1 = 8 loads); need A0,B0 -> vmcnt(4)
  STAGE_A(0, 0, 0); STAGE_B(0, 0, 0); STAGE_A(0, 1, 0); STAGE_B(0, 1, 0);
  WAIT_VM4;
  BAR;

  for (int k2 = 0; k2 < 31; ++k2) {
    TILE(0, 1, 2 * k2 + 1, 1, 0);
    TILE(1, 0, 2 * k2 + 2, 1, 0);
  }
  TILE(0, 1, 63, 1, 0);
  TILE(1, 0, 64, 0, 1);

  // epilogue: C/D layout col = lane&15, row = (lane>>4)*4 + j  (nontemporal)
  const size_t crow0 = (size_t)tm * 256 + wm + (lane >> 4) * 4;
  const int ccol0 = tn * 256 + wn + fr;
#pragma unroll
  for (int mf = 0; mf < 8; ++mf)
#pragma unroll
    for (int j = 0; j < 4; ++j) {
      float* Cp = C + (crow0 + mf * 16 + j) * 4096 + ccol0;
#pragma unroll
      for (int nf = 0; nf < 4; ++nf)
        __builtin_nontemporal_store(acc[mf][nf][j], Cp + nf * 16);
    }
}

// ---------------------------------------------------------------------------
extern "C" void kernel_launch(void* const* d_in, const int* in_sizes, int n_in,
                              void* d_out, int out_size, void* d_ws, size_t ws_size,
                              hipStream_t stream) {
  const float* x      = (const float*)d_in[0];
  const int*   Qidxs  = (const int*)d_in[1];
  const float* SU     = (const float*)d_in[2];
  const float* SV     = (const float*)d_in[3];
  const float* Wscale = (const float*)d_in[4];
  const float* cb     = (const float*)d_in[5];
  float* out = (float*)d_out;

  unsigned short* Z  = (unsigned short*)d_ws;                                      // 64 MB
  unsigned short* Wa = (unsigned short*)((char*)d_ws + (size_t)64 * 1024 * 1024);  // 32 MB
  unsigned short* Wb = (unsigned short*)((char*)d_ws + (size_t)96 * 1024 * 1024);  // 32 MB

  zconv_decode_kernel<<<12288, 256, 0, stream>>>(x, SV, Z, Qidxs, cb, Wa);
  fht_wcol_kernel<0><<<1024, 256, 0, stream>>>(Wa, Wb, SU, Wscale);
  fht_wcol_kernel<1><<<1024, 256, 0, stream>>>(Wb, Wa, SU, Wscale);
  gemm_bt_kernel<<<512, 512, 0, stream>>>(Z, Wa, out);
}

// Round 17
// 341.395 us; speedup vs baseline: 1.1001x; 1.0073x over previous
//
#include <hip/hip_runtime.h>
#include <hip/hip_bf16.h>

// ---------------------------------------------------------------------------
// E8 RHT Linear:  y = SU * FHT( FHT(SV * x) @ Wr^T * Wscale )
// Identity used:  y = (SV*x) @ W5^T,  W5 = diag(SU*Wscale) * (H Wr H)/4096
// GEMM: r5/r9-exact K-loop (frozen) + scalar nt C stores (r12/r16 best).
// r17: wcol LDS exchange in bf16 (32 KB -> 5 blocks/CU, 2.5x TLP).
// ---------------------------------------------------------------------------

using short8   = __attribute__((ext_vector_type(8))) short;
using f32x4    = __attribute__((ext_vector_type(4))) float;
using ushort4v = __attribute__((ext_vector_type(4))) unsigned short;

#define AS1 __attribute__((address_space(1)))
#define AS3 __attribute__((address_space(3)))

__device__ __forceinline__ unsigned short f2bf(float f) {
  unsigned int u = __float_as_uint(f);
  unsigned int r = (u + 0x7fffu + ((u >> 16) & 1u)) >> 16;
  return (unsigned short)r;
}

__device__ __forceinline__ float bf2f(unsigned short u) {
  return __uint_as_float((unsigned int)u << 16);
}

__device__ __forceinline__ void gload16(const void* g, void* l) {
  __builtin_amdgcn_global_load_lds((const AS1 void*)g, (AS3 void*)l, 16, 0, 0);
}

#define WAIT_VM4 asm volatile("s_waitcnt vmcnt(4)" ::: "memory")
#define WAIT_VM0 asm volatile("s_waitcnt vmcnt(0)" ::: "memory")
#define LGKM0    asm volatile("s_waitcnt lgkmcnt(0)" ::: "memory")
#define SB       __builtin_amdgcn_sched_barrier(0)
#define BAR      __builtin_amdgcn_s_barrier()
#define PRIO1    __builtin_amdgcn_s_setprio(1)
#define PRIO0    __builtin_amdgcn_s_setprio(0)

// H16 butterflies over register index j (elem distance 1,2,4,8)
#define H16_REGS(v)                                                       \
  _Pragma("unroll")                                                       \
  for (int d = 1; d < 16; d <<= 1) {                                      \
    _Pragma("unroll")                                                     \
    for (int j = 0; j < 16; ++j) {                                        \
      if ((j & d) == 0) {                                                 \
        float a_ = v[j], b_ = v[j | d];                                   \
        v[j] = a_ + b_;                                                   \
        v[j | d] = a_ - b_;                                               \
      }                                                                   \
    }                                                                     \
  }

// ---------------------------------------------------------------------------
// Kernel 1 (fused): blocks [0,8192): z = bf16(SV*x) elementwise;
// blocks [8192,12288): Wa[row] = FHT_4096(decode(Qidxs[row]))/64.
// ---------------------------------------------------------------------------
__global__ __launch_bounds__(256) void zconv_decode_kernel(const float* __restrict__ X,
                                                           const float* __restrict__ SV,
                                                           unsigned short* __restrict__ Z,
                                                           const int* __restrict__ Q,
                                                           const float* __restrict__ cb,
                                                           unsigned short* __restrict__ Wa) {
  __shared__ float tmp[4096];
  const int t = threadIdx.x;
  if (blockIdx.x < 8192) {
    // ---- zconv ----
    const size_t idx = ((size_t)blockIdx.x * 256 + t) * 16;
    const int c0 = (int)(idx & 4095);
    const float4* X4 = (const float4*)(X + idx);
    const float4* SV4 = (const float4*)(SV + c0);
    union { short8 s; unsigned short u[8]; } lo, hi;
#pragma unroll
    for (int q = 0; q < 2; ++q) {
      float4 a = X4[2 * q], b = X4[2 * q + 1];
      float4 sa = SV4[2 * q], sb = SV4[2 * q + 1];
      unsigned short* o = q ? hi.u : lo.u;
      o[0] = f2bf(a.x * sa.x); o[1] = f2bf(a.y * sa.y);
      o[2] = f2bf(a.z * sa.z); o[3] = f2bf(a.w * sa.w);
      o[4] = f2bf(b.x * sb.x); o[5] = f2bf(b.y * sb.y);
      o[6] = f2bf(b.z * sb.z); o[7] = f2bf(b.w * sb.w);
    }
    short8* Zp = (short8*)(Z + idx);
    Zp[0] = lo.s;
    Zp[1] = hi.s;
  } else {
    // ---- decode + row FHT ----
    const int row = blockIdx.x - 8192;
    const int lane = t & 63;
    float v[16];
    int2 qi = *(const int2*)&Q[(size_t)row * 512 + 2 * t];
    {
      const float4* c0 = (const float4*)(cb + (size_t)qi.x * 8);
      const float4* c1 = (const float4*)(cb + (size_t)qi.y * 8);
      float4 p0 = c0[0], p1 = c0[1], p2 = c1[0], p3 = c1[1];
      v[0] = p0.x;  v[1] = p0.y;  v[2] = p0.z;  v[3] = p0.w;
      v[4] = p1.x;  v[5] = p1.y;  v[6] = p1.z;  v[7] = p1.w;
      v[8] = p2.x;  v[9] = p2.y;  v[10] = p2.z; v[11] = p2.w;
      v[12] = p3.x; v[13] = p3.y; v[14] = p3.z; v[15] = p3.w;
    }
    H16_REGS(v)
#pragma unroll
    for (int d = 1; d < 64; d <<= 1) {
#pragma unroll
      for (int j = 0; j < 16; ++j) {
        float p_ = __shfl_xor(v[j], d, 64);
        v[j] = (lane & d) ? (p_ - v[j]) : (v[j] + p_);
      }
    }
#pragma unroll
    for (int dd = 0; dd < 2; ++dd) {
      const int d = 64 << dd;
      if (dd) __syncthreads();
#pragma unroll
      for (int j = 0; j < 16; ++j) tmp[j * 256 + t] = v[j];
      __syncthreads();
#pragma unroll
      for (int j = 0; j < 16; ++j) {
        float p_ = tmp[j * 256 + (t ^ d)];
        v[j] = (t & d) ? (p_ - v[j]) : (v[j] + p_);
      }
    }
    union { short8 s; unsigned short u[8]; } lo, hi;
#pragma unroll
    for (int j = 0; j < 8; ++j) {
      lo.u[j] = f2bf(v[j] * (1.0f / 64.0f));
      hi.u[j] = f2bf(v[8 + j] * (1.0f / 64.0f));
    }
    short8* Wp = (short8*)(Wa + (size_t)row * 4096 + t * 16);
    Wp[0] = lo.s;
    Wp[1] = hi.s;
  }
}

// ---------------------------------------------------------------------------
// Kernels 2a/2b: column-FHT of W (over row index), pass0 = row-bits 0-5,
// pass1 = row-bits 6-11 (applies SU[row]*Wscale/8; pass0 applies 1/8).
// Block = 64 rows x 256 cols, 256 threads; thread = 16 rows x 4 cols.
// r17: LDS exchange in bf16 (32 KB -> 5 blocks/CU vs 2 at f32).
// ---------------------------------------------------------------------------
template <int PASS>
__global__ __launch_bounds__(256) void fht_wcol_kernel(const unsigned short* __restrict__ Win,
                                                       unsigned short* __restrict__ Wout,
                                                       const float* __restrict__ SU,
                                                       const float* __restrict__ Wscale) {
  __shared__ unsigned short tmp2[64 * 256];   // 32 KB (bf16 exchange)
  const int rg = blockIdx.x >> 4;
  const int cg = blockIdx.x & 15;
  const int t = threadIdx.x;
  const int cq = t & 63;
  const int q = t >> 6;
  const int c0 = cg * 256 + cq * 4;
  f32x4 v[16];
#pragma unroll
  for (int j = 0; j < 16; ++j) {
    const int rloc = q * 16 + j;
    const int row = (PASS == 0) ? (rg * 64 + rloc) : (rloc * 64 + rg);
    ushort4v u = *(const ushort4v*)&Win[(size_t)row * 4096 + c0];
    v[j][0] = bf2f(u[0]); v[j][1] = bf2f(u[1]);
    v[j][2] = bf2f(u[2]); v[j][3] = bf2f(u[3]);
  }
#pragma unroll
  for (int d = 1; d < 16; d <<= 1) {
#pragma unroll
    for (int j = 0; j < 16; ++j) {
      if ((j & d) == 0) {
        f32x4 a_ = v[j], b_ = v[j | d];
        v[j] = a_ + b_;
        v[j | d] = a_ - b_;
      }
    }
  }
#pragma unroll
  for (int dd = 0; dd < 2; ++dd) {
    const int d = 16 << dd;
    if (dd) __syncthreads();
#pragma unroll
    for (int j = 0; j < 16; ++j) {
      ushort4v w;
      w[0] = f2bf(v[j][0]); w[1] = f2bf(v[j][1]);
      w[2] = f2bf(v[j][2]); w[3] = f2bf(v[j][3]);
      *(ushort4v*)&tmp2[(q * 16 + j) * 256 + cq * 4] = w;
    }
    __syncthreads();
#pragma unroll
    for (int j = 0; j < 16; ++j) {
      const int rloc = q * 16 + j;
      ushort4v u = *(const ushort4v*)&tmp2[(rloc ^ d) * 256 + cq * 4];
      f32x4 p_;
      p_[0] = bf2f(u[0]); p_[1] = bf2f(u[1]);
      p_[2] = bf2f(u[2]); p_[3] = bf2f(u[3]);
      v[j] = (rloc & d) ? (p_ - v[j]) : (v[j] + p_);
    }
  }
  if (PASS == 0) {
#pragma unroll
    for (int j = 0; j < 16; ++j) {
      const int row = rg * 64 + q * 16 + j;
      ushort4v w;
      w[0] = f2bf(v[j][0] * 0.125f); w[1] = f2bf(v[j][1] * 0.125f);
      w[2] = f2bf(v[j][2] * 0.125f); w[3] = f2bf(v[j][3] * 0.125f);
      *(ushort4v*)&Wout[(size_t)row * 4096 + c0] = w;
    }
  } else {
    const float ws = Wscale[0] * 0.125f;
#pragma unroll
    for (int j = 0; j < 16; ++j) {
      const int row = (q * 16 + j) * 64 + rg;
      const float s = SU[row] * ws;
      ushort4v w;
      w[0] = f2bf(v[j][0] * s); w[1] = f2bf(v[j][1] * s);
      w[2] = f2bf(v[j][2] * s); w[3] = f2bf(v[j][3] * s);
      *(ushort4v*)&Wout[(size_t)row * 4096 + c0] = w;
    }
  }
}

// ---------------------------------------------------------------------------
// Kernel 3: C[8192][4096] f32 = Z @ W5^T — r5-exact 8-phase K-loop (frozen).
// Staging per tile: P1: A0, P2: B0, P3: A1, P4: B1 (2 gload_lds each).
// Waits: vmcnt(4) @P2-mid, vmcnt(4) @P4-end. XOR swizzle (0 conflicts, r3).
// Epilogue: scalar nontemporal stores (r12-exact, measured best).
// ---------------------------------------------------------------------------
#define MFMA1(mi, ni, av, bv) \
  acc[mi][ni] = __builtin_amdgcn_mfma_f32_16x16x32_bf16(av, bv, acc[mi][ni], 0, 0, 0)

#define MFMA16(MB, a0_, a1_, a2_, a3_, bx0, bx1, bx2, bx3) do {           \
  MFMA1(MB + 0, 0, a0_, bx0); MFMA1(MB + 0, 1, a0_, bx1);                 \
  MFMA1(MB + 0, 2, a0_, bx2); MFMA1(MB + 0, 3, a0_, bx3);                 \
  MFMA1(MB + 1, 0, a1_, bx0); MFMA1(MB + 1, 1, a1_, bx1);                 \
  MFMA1(MB + 1, 2, a1_, bx2); MFMA1(MB + 1, 3, a1_, bx3);                 \
  MFMA1(MB + 2, 0, a2_, bx0); MFMA1(MB + 2, 1, a2_, bx1);                 \
  MFMA1(MB + 2, 2, a2_, bx2); MFMA1(MB + 2, 3, a2_, bx3);                 \
  MFMA1(MB + 3, 0, a3_, bx0); MFMA1(MB + 3, 1, a3_, bx1);                 \
  MFMA1(MB + 3, 2, a3_, bx2); MFMA1(MB + 3, 3, a3_, bx3);                 \
} while (0)

#define RD_A4(r0, r1, r2, r3, BC, KS, MB) do {                            \
  r0 = *(const short8*)&sA[BC][KS][wm + (MB + 0) * 16 + fr][qc];          \
  r1 = *(const short8*)&sA[BC][KS][wm + (MB + 1) * 16 + fr][qc];          \
  r2 = *(const short8*)&sA[BC][KS][wm + (MB + 2) * 16 + fr][qc];          \
  r3 = *(const short8*)&sA[BC][KS][wm + (MB + 3) * 16 + fr][qc];          \
} while (0)

#define RD_B4(r0, r1, r2, r3, BC, KS) do {                                \
  r0 = *(const short8*)&sB[BC][KS][wn + 0 * 16 + fr][qc];                 \
  r1 = *(const short8*)&sB[BC][KS][wn + 1 * 16 + fr][qc];                 \
  r2 = *(const short8*)&sB[BC][KS][wn + 2 * 16 + fr][qc];                 \
  r3 = *(const short8*)&sB[BC][KS][wn + 3 * 16 + fr][qc];                 \
} while (0)

#define STAGE_A(BB, H, KTN) do {                                          \
  const unsigned short* gp_ = Ag + (KTN) * 64 + (H) * 32;                 \
  gload16(gp_, (unsigned short*)&sA[BB][H][0][0] + d0);                   \
  gload16(gp_ + (size_t)128 * 4096, (unsigned short*)&sA[BB][H][0][0] + d1); \
} while (0)

#define STAGE_B(BB, H, KTN) do {                                          \
  const unsigned short* gp_ = Bg + (KTN) * 64 + (H) * 32;                 \
  gload16(gp_, (unsigned short*)&sB[BB][H][0][0] + d0);                   \
  gload16(gp_ + (size_t)128 * 4096, (unsigned short*)&sB[BB][H][0][0] + d1); \
} while (0)

#define TILE(BC, BN_, KTN, DS, LASTF) do {                                \
  /* P1: top-read own frags (khalf0), prefetch aS1 during MFMA */         \
  RD_A4(aS0_0, aS0_1, aS0_2, aS0_3, BC, 0, 0);                            \
  RD_B4(bA_0, bA_1, bA_2, bA_3, BC, 0);                                   \
  if (DS) { STAGE_A(BN_, 0, KTN); }                                       \
  BAR; LGKM0; SB;                                                         \
  RD_A4(aS1_0, aS1_1, aS1_2, aS1_3, BC, 0, 4); SB;                        \
  PRIO1; MFMA16(0, aS0_0, aS0_1, aS0_2, aS0_3, bA_0, bA_1, bA_2, bA_3);   \
  PRIO0; BAR;                                                             \
  /* P2: vmcnt guards khalf1, then prefetch khalf1 frags */               \
  if (DS) { STAGE_B(BN_, 0, KTN); }                                       \
  BAR; LGKM0; SB;                                                         \
  if (LASTF) { WAIT_VM0; } else { WAIT_VM4; }                             \
  RD_A4(aS0_0, aS0_1, aS0_2, aS0_3, BC, 1, 0);                            \
  RD_B4(bB_0, bB_1, bB_2, bB_3, BC, 1); SB;                               \
  PRIO1; MFMA16(4, aS1_0, aS1_1, aS1_2, aS1_3, bA_0, bA_1, bA_2, bA_3);   \
  PRIO0; BAR;                                                             \
  /* P3: prefetch aS1 (khalf1 mb4-7) */                                   \
  if (DS) { STAGE_A(BN_, 1, KTN); }                                       \
  BAR; LGKM0; SB;                                                         \
  RD_A4(aS1_0, aS1_1, aS1_2, aS1_3, BC, 1, 4); SB;                        \
  PRIO1; MFMA16(0, aS0_0, aS0_1, aS0_2, aS0_3, bB_0, bB_1, bB_2, bB_3);   \
  PRIO0; BAR;                                                             \
  /* P4: no prefetch (next tile P1 reads after its own guard) */          \
  if (DS) { STAGE_B(BN_, 1, KTN); }                                       \
  BAR; LGKM0; SB;                                                         \
  PRIO1; MFMA16(4, aS1_0, aS1_1, aS1_2, aS1_3, bB_0, bB_1, bB_2, bB_3);   \
  PRIO0;                                                                  \
  if (!(LASTF)) { WAIT_VM4; }                                             \
  BAR;                                                                    \
} while (0)

__global__ __launch_bounds__(512, 2) void gemm_bt_kernel(const unsigned short* __restrict__ A,
                                                         const unsigned short* __restrict__ B,
                                                         float* __restrict__ C) {
  __shared__ unsigned short sA[2][2][256][32];
  __shared__ unsigned short sB[2][2][256][32];

  const int bid = blockIdx.x;                    // 512 blocks = 32 tm x 16 tn
  const int swz = (bid & 7) * 64 + (bid >> 3);   // XCD swizzle (512 % 8 == 0)
  const int tm = swz >> 4;                       // 0..31
  const int tn = swz & 15;                       // 0..15

  const int t = threadIdx.x;
  const int lane = t & 63;
  const int w = t >> 6;
  const int wm = (w >> 2) * 128;                 // wave M offset (2 waves)
  const int wn = (w & 3) * 64;                   // wave N offset (4 waves)
  const int fr = lane & 15;
  // read-side swizzled k-chunk: global chunk g=lane>>4 lives at LDS chunk
  // g ^ ((row>>1)&3); row bits 1-2 == lane bits 1-2 (wm/wn/mb*16 touch bits>=4)
  const int qc = ((lane >> 4) ^ ((lane >> 1) & 3)) * 8;

  // staging: thread t covers LDS row sr=t>>2 (and sr+128), LDS chunk t&3;
  // source global chunk = (t&3) ^ swz(row), swz(row) = (row>>1)&3 = (t>>3)&3.
  const int sr = t >> 2;                         // 0..127
  const int sc = ((t & 3) ^ ((t >> 3) & 3)) * 8; // source k-chunk within half
  const unsigned short* Ag = A + (size_t)(tm * 256 + sr) * 4096 + sc;
  const unsigned short* Bg = B + (size_t)(tn * 256 + sr) * 4096 + sc;
  const int d0 = t * 8;                          // dest elem offset, load 0
  const int d1 = (512 + t) * 8;                  // dest elem offset, load 1

  f32x4 acc[8][4];
#pragma unroll
  for (int m = 0; m < 8; ++m)
#pragma unroll
    for (int n = 0; n < 4; ++n) {
      f32x4 z = {0.f, 0.f, 0.f, 0.f};
      acc[m][n] = z;
    }
  short8 aS0_0, aS0_1, aS0_2, aS0_3;
  short8 aS1_0, aS1_1, aS1_2, aS1_3;
  short8 bA_0, bA_1, bA_2, bA_3;
  short8 bB_0, bB_1, bB_2, bB_3;

  // prologue: stage tile 0 (A0,B0,A1,B1 = 8 loads); need A0,B0 -> vmcnt(4)
  STAGE_A(0, 0, 0); STAGE_B(0, 0, 0); STAGE_A(0, 1, 0); STAGE_B(0, 1, 0);
  WAIT_VM4;
  BAR;

  for (int k2 = 0; k2 < 31; ++k2) {
    TILE(0, 1, 2 * k2 + 1, 1, 0);
    TILE(1, 0, 2 * k2 + 2, 1, 0);
  }
  TILE(0, 1, 63, 1, 0);
  TILE(1, 0, 64, 0, 1);

  // epilogue: C/D layout col = lane&15, row = (lane>>4)*4 + j  (nontemporal)
  const size_t crow0 = (size_t)tm * 256 + wm + (lane >> 4) * 4;
  const int ccol0 = tn * 256 + wn + fr;
#pragma unroll
  for (int mf = 0; mf < 8; ++mf)
#pragma unroll
    for (int j = 0; j < 4; ++j) {
      float* Cp = C + (crow0 + mf * 16 + j) * 4096 + ccol0;
#pragma unroll
      for (int nf = 0; nf < 4; ++nf)
        __builtin_nontemporal_store(acc[mf][nf][j], Cp + nf * 16);
    }
}

// ---------------------------------------------------------------------------
extern "C" void kernel_launch(void* const* d_in, const int* in_sizes, int n_in,
                              void* d_out, int out_size, void* d_ws, size_t ws_size,
                              hipStream_t stream) {
  const float* x      = (const float*)d_in[0];
  const int*   Qidxs  = (const int*)d_in[1];
  const float* SU     = (const float*)d_in[2];
  const float* SV     = (const float*)d_in[3];
  const float* Wscale = (const float*)d_in[4];
  const float* cb     = (const float*)d_in[5];
  float* out = (float*)d_out;

  unsigned short* Z  = (unsigned short*)d_ws;                                      // 64 MB
  unsigned short* Wa = (unsigned short*)((char*)d_ws + (size_t)64 * 1024 * 1024);  // 32 MB
  unsigned short* Wb = (unsigned short*)((char*)d_ws + (size_t)96 * 1024 * 1024);  // 32 MB

  zconv_decode_kernel<<<12288, 256, 0, stream>>>(x, SV, Z, Qidxs, cb, Wa);
  fht_wcol_kernel<0><<<1024, 256, 0, stream>>>(Wa, Wb, SU, Wscale);
  fht_wcol_kernel<1><<<1024, 256, 0, stream>>>(Wb, Wa, SU, Wscale);
  gemm_bt_kernel<<<512, 512, 0, stream>>>(Z, Wa, out);
}